// Round 1
// baseline (1010.976 us; speedup 1.0000x reference)
//
#include <hip/hip_runtime.h>

// VectorQuantizer (VAR-style multi-scale residual VQ) forward on gfx950.
// B=32, C=64, L=512, V=8192, scales {1..512}, Phi idx table [0,0,1,1,1,2,2,3,3,3]
// (exact fp64 tie-break analysis of np.linspace(1/12,11/12,4) vs si/9).
// Workspace need: ~19.1 MB.

#define B_ 32
#define C_ 64
#define L_ 512
#define V_ 8192

__device__ __forceinline__ unsigned enc_f(float s) {
  unsigned u = __float_as_uint(s);
  return (u & 0x80000000u) ? ~u : (u | 0x80000000u);
}

// ---------- prep: embed transpose [C][V] + reciprocal row norms ----------
__global__ __launch_bounds__(256) void k_prep(const float* __restrict__ embed,
                                              float* __restrict__ embedT,
                                              float* __restrict__ rnorm) {
  int v = blockIdx.x * 256 + threadIdx.x;
  if (v >= V_) return;
  const float* row = embed + v * C_;
  float s0 = 0.f, s1 = 0.f, s2 = 0.f, s3 = 0.f;
#pragma unroll
  for (int c4 = 0; c4 < 16; c4++) {
    float4 x = *(const float4*)(row + c4 * 4);
    s0 = fmaf(x.x, x.x, s0);
    s1 = fmaf(x.y, x.y, s1);
    s2 = fmaf(x.z, x.z, s2);
    s3 = fmaf(x.w, x.w, s3);
    embedT[(c4 * 4 + 0) * V_ + v] = x.x;
    embedT[(c4 * 4 + 1) * V_ + v] = x.y;
    embedT[(c4 * 4 + 2) * V_ + v] = x.z;
    embedT[(c4 * 4 + 3) * V_ + v] = x.w;
  }
  float nrm = sqrtf((s0 + s1) + (s2 + s3));
  rnorm[v] = 1.0f / fmaxf(nrm, 1e-12f);
}

// ---------- init: zero f_hat (in d_out) and loss accumulators ----------
__global__ __launch_bounds__(256) void k_init(float* __restrict__ fhat,
                                              float* __restrict__ lossac) {
  int i = blockIdx.x * 256 + threadIdx.x;
  if (i < B_ * C_ * L_) fhat[i] = 0.0f;
  if (i < 16) lossac[i] = 0.0f;
}

// ---------- downsample residual (f - f_hat) to [C][Q] (transposed), zero packed ----------
__global__ __launch_bounds__(256) void k_down(const float* __restrict__ f,
                                              const float* __restrict__ fhat,
                                              float* __restrict__ restqT,
                                              unsigned long long* __restrict__ packed,
                                              int Q, int log2Q, int log2s, int blk) {
  int g = blockIdx.x * 256 + threadIdx.x;  // Q*64 threads
  int q = g & (Q - 1);
  int c = g >> log2Q;
  int b = q >> log2s;
  int j = q - (b << log2s);
  const int base = ((b << 6) + c) * L_ + j * blk;
  float s0 = 0.f, s1 = 0.f, s2 = 0.f, s3 = 0.f;
  int t = 0;
  for (; t + 4 <= blk; t += 4) {
    s0 += f[base + t]     - fhat[base + t];
    s1 += f[base + t + 1] - fhat[base + t + 1];
    s2 += f[base + t + 2] - fhat[base + t + 2];
    s3 += f[base + t + 3] - fhat[base + t + 3];
  }
  for (; t < blk; t++) s0 += f[base + t] - fhat[base + t];
  restqT[c * Q + q] = ((s0 + s1) + (s2 + s3)) * (1.0f / (float)blk);
  if (g < Q) packed[g] = 0ull;
}

// ---------- argmax over codebook: block = 32 queries, lane = 4 codes x 8 queries ----------
__global__ __launch_bounds__(256) void k_argmax(const float* __restrict__ embedT,
                                                const float* __restrict__ rnorm,
                                                const float* __restrict__ restqT,
                                                unsigned long long* __restrict__ packed,
                                                int Q, int qtiles, int codes_per) {
  int qt = blockIdx.x % qtiles;
  int sp = blockIdx.x / qtiles;
  int lane = threadIdx.x & 63;
  int wave = threadIdx.x >> 6;
  int qbase = qt * 32;
  __shared__ float qlds[64][32];
  for (int i = threadIdx.x; i < 64 * 32; i += 256) {
    int c = i >> 5, qq = i & 31;
    qlds[c][qq] = restqT[c * Q + qbase + qq];
  }
  __syncthreads();

  float best[8];
  int bidx[8];
#pragma unroll
  for (int i = 0; i < 8; i++) { best[i] = -3.4e38f; bidx[i] = 0; }

  const int qoff = wave * 8;
  const int cb = sp * codes_per + lane * 4;
  for (int chunk = 0; chunk < codes_per; chunk += 256) {
    const int code0 = cb + chunk;
    float acc[4][8];
#pragma unroll
    for (int k = 0; k < 4; k++)
#pragma unroll
      for (int qq = 0; qq < 8; qq++) acc[k][qq] = 0.0f;

#pragma unroll 4
    for (int cc = 0; cc < 64; cc++) {
      const float4 cd = *(const float4*)(embedT + cc * V_ + code0);
      const float4 qa = *(const float4*)(&qlds[cc][qoff]);
      const float4 qb = *(const float4*)(&qlds[cc][qoff + 4]);
      float qv[8] = {qa.x, qa.y, qa.z, qa.w, qb.x, qb.y, qb.z, qb.w};
#pragma unroll
      for (int qq = 0; qq < 8; qq++) {
        acc[0][qq] = fmaf(cd.x, qv[qq], acc[0][qq]);
        acc[1][qq] = fmaf(cd.y, qv[qq], acc[1][qq]);
        acc[2][qq] = fmaf(cd.z, qv[qq], acc[2][qq]);
        acc[3][qq] = fmaf(cd.w, qv[qq], acc[3][qq]);
      }
    }
    const float4 rn = *(const float4*)(rnorm + code0);
    const float rnv[4] = {rn.x, rn.y, rn.z, rn.w};
#pragma unroll
    for (int k = 0; k < 4; k++) {
      const int cid = code0 + k;
#pragma unroll
      for (int qq = 0; qq < 8; qq++) {
        float sc = acc[k][qq] * rnv[k];
        if (sc > best[qq] || (sc == best[qq] && cid < bidx[qq])) {
          best[qq] = sc; bidx[qq] = cid;
        }
      }
    }
  }
  // wave butterfly argmax (tie -> lowest index, matches jnp.argmax first-max)
#pragma unroll
  for (int off = 1; off < 64; off <<= 1) {
#pragma unroll
    for (int qq = 0; qq < 8; qq++) {
      float ob = __shfl_xor(best[qq], off);
      int oi = __shfl_xor(bidx[qq], off);
      if (ob > best[qq] || (ob == best[qq] && oi < bidx[qq])) {
        best[qq] = ob; bidx[qq] = oi;
      }
    }
  }
  if (lane == 0) {
#pragma unroll
    for (int qq = 0; qq < 8; qq++) {
      unsigned long long pk =
          ((unsigned long long)enc_f(best[qq]) << 32) | (unsigned)(~bidx[qq]);
      atomicMax(&packed[qbase + qoff + qq], pk);
    }
  }
}

// ---------- per-segment conv matvecs: abc[q][192] = {W_-1 h, W_0 h, W_+1 h} ----------
__global__ __launch_bounds__(256) void k_matvec(const float* __restrict__ embed,
                                                const float* __restrict__ phiw,
                                                const unsigned long long* __restrict__ packed,
                                                float* __restrict__ abc,
                                                int pidx) {
  __shared__ float wl[3][64][65];  // +1 pad breaks write-bank aliasing
  __shared__ float hl[64][16];
  const float* pw = phiw + pidx * (64 * 64 * 3);
  for (int i = threadIdx.x; i < 64 * 64 * 3; i += 256) {
    int o = i / 192;
    int r = i - o * 192;
    int c = r / 3;
    int t = r - c * 3;
    wl[t][c][o] = pw[i];  // global read coalesced
  }
  const int qbase = blockIdx.x * 16;
  for (int i = threadIdx.x; i < 16 * 64; i += 256) {
    int qq = i & 15, c = i >> 4;
    int idx = (int)(~(unsigned)(packed[qbase + qq]));
    hl[c][qq] = embed[idx * C_ + c];
  }
  __syncthreads();

  const int o = threadIdx.x & 63;
  const int q0 = (threadIdx.x >> 6) * 4;
  float a0[3][4];
#pragma unroll
  for (int t = 0; t < 3; t++)
#pragma unroll
    for (int qq = 0; qq < 4; qq++) a0[t][qq] = 0.0f;

#pragma unroll 4
  for (int c = 0; c < 64; c++) {
    const float4 h4 = *(const float4*)(&hl[c][q0]);  // broadcast
    const float w0 = wl[0][c][o], w1 = wl[1][c][o], w2 = wl[2][c][o];
    const float hv[4] = {h4.x, h4.y, h4.z, h4.w};
#pragma unroll
    for (int qq = 0; qq < 4; qq++) {
      a0[0][qq] = fmaf(w0, hv[qq], a0[0][qq]);
      a0[1][qq] = fmaf(w1, hv[qq], a0[1][qq]);
      a0[2][qq] = fmaf(w2, hv[qq], a0[2][qq]);
    }
  }
#pragma unroll
  for (int t = 0; t < 3; t++)
#pragma unroll
    for (int qq = 0; qq < 4; qq++)
      abc[(qbase + q0 + qq) * 192 + t * 64 + o] = a0[t][qq];
}

// ---------- apply: h_out = 0.5h + 0.5(conv+bias); f_hat += h_out; loss partial ----------
__global__ __launch_bounds__(256) void k_apply(const float* __restrict__ f,
                                               const float* __restrict__ embed,
                                               const float* __restrict__ phib,
                                               const unsigned long long* __restrict__ packed,
                                               const float* __restrict__ abc,
                                               float* __restrict__ fhat,
                                               float* __restrict__ lossac,
                                               int s, int log2blk, int blk, int pidx, int si) {
  const int g = blockIdx.x * 256 + threadIdx.x;  // B*16*L threads
  const int l = g & 511;
  const int c4 = (g >> 9) & 15;
  const int b = g >> 13;
  const int j = l >> log2blk;
  const int pos = l & (blk - 1);
  const int q = b * s + j;
  const int idx = (int)(~(unsigned)(packed[q]));
  const bool la = (pos == 0), rc = (pos == blk - 1);
  const int ja = la ? j - 1 : j;
  const int jc = rc ? j + 1 : j;
  const int c0 = c4 * 4;

  float4 a4 = make_float4(0.f, 0.f, 0.f, 0.f);
  float4 cc4 = make_float4(0.f, 0.f, 0.f, 0.f);
  if (ja >= 0) a4 = *(const float4*)(abc + (b * s + ja) * 192 + c0);
  const float4 b4 = *(const float4*)(abc + q * 192 + 64 + c0);
  if (jc < s) cc4 = *(const float4*)(abc + (b * s + jc) * 192 + 128 + c0);
  const float4 h4 = *(const float4*)(embed + idx * C_ + c0);
  const float4 bi = *(const float4*)(phib + pidx * C_ + c0);

  const float av[4] = {a4.x, a4.y, a4.z, a4.w};
  const float bv[4] = {b4.x, b4.y, b4.z, b4.w};
  const float cv[4] = {cc4.x, cc4.y, cc4.z, cc4.w};
  const float hv[4] = {h4.x, h4.y, h4.z, h4.w};
  const float biv[4] = {bi.x, bi.y, bi.z, bi.w};

  float sq = 0.0f;
#pragma unroll
  for (int i = 0; i < 4; i++) {
    float y = ((av[i] + bv[i]) + cv[i]) + biv[i];
    float ho = 0.5f * (hv[i] + y);
    int fi = ((b << 6) + c0 + i) * L_ + l;
    float fh = fhat[fi] + ho;
    fhat[fi] = fh;
    float d = fh - f[fi];
    sq = fmaf(d, d, sq);
  }
#pragma unroll
  for (int off = 32; off > 0; off >>= 1) sq += __shfl_down(sq, off);
  __shared__ float red[4];
  const int lane = threadIdx.x & 63, wave = threadIdx.x >> 6;
  if (lane == 0) red[wave] = sq;
  __syncthreads();
  if (threadIdx.x == 0)
    atomicAdd(&lossac[si], (red[0] + red[1]) + (red[2] + red[3]));
}

// ---------- final loss ----------
__global__ void k_loss(const float* __restrict__ lossac, float* __restrict__ out) {
  if (threadIdx.x == 0 && blockIdx.x == 0) {
    float sum = 0.f;
    for (int i = 0; i < 10; i++) sum += lossac[i];
    // loss = sum_si 1.25 * mse_si / 10 ; mse = sq_sum / (B*C*L)
    out[B_ * C_ * L_] = sum * (1.25f / (10.0f * (float)(B_ * C_ * L_)));
  }
}

extern "C" void kernel_launch(void* const* d_in, const int* in_sizes, int n_in,
                              void* d_out, int out_size, void* d_ws, size_t ws_size,
                              hipStream_t stream) {
  const float* f     = (const float*)d_in[0];  // [32][64][512]
  const float* embed = (const float*)d_in[1];  // [8192][64]
  const float* phiw  = (const float*)d_in[2];  // [4][64][64][3]
  const float* phib  = (const float*)d_in[3];  // [4][64]
  float* fhat = (float*)d_out;                 // f_hat lives in d_out[0..1048575], loss at [1048576]

  float* ws = (float*)d_ws;
  float* embedT = ws;                             // 64*8192
  float* rnorm  = embedT + C_ * V_;               // 8192
  float* restqT = rnorm + V_;                     // 64*16384 max
  float* abc    = restqT + 64 * 16384;            // 16384*192
  float* lossac = abc + 16384 * 192;              // 16
  unsigned long long* packed = (unsigned long long*)(lossac + 16);  // 16384 u64

  hipLaunchKernelGGL(k_prep, dim3(V_ / 256), dim3(256), 0, stream, embed, embedT, rnorm);
  hipLaunchKernelGGL(k_init, dim3((B_ * C_ * L_) / 256), dim3(256), 0, stream, fhat, lossac);

  static const int SEG[10]  = {1, 2, 4, 8, 16, 32, 64, 128, 256, 512};
  static const int PIDX[10] = {0, 0, 1, 1, 1, 2, 2, 3, 3, 3};
  static const int NSPL[10] = {32, 32, 32, 32, 32, 32, 16, 8, 4, 2};

  for (int si = 0; si < 10; si++) {
    const int s = SEG[si];
    int log2s = 0;
    while ((1 << log2s) < s) log2s++;
    const int Q = 32 * s;
    const int log2Q = 5 + log2s;
    const int blk = L_ / s;
    const int log2blk = 9 - log2s;
    const int qtiles = Q / 32;
    const int nsplit = NSPL[si];
    const int codes_per = V_ / nsplit;

    hipLaunchKernelGGL(k_down, dim3((Q * 64) / 256), dim3(256), 0, stream,
                       f, fhat, restqT, packed, Q, log2Q, log2s, blk);
    hipLaunchKernelGGL(k_argmax, dim3(qtiles * nsplit), dim3(256), 0, stream,
                       embedT, rnorm, restqT, packed, Q, qtiles, codes_per);
    hipLaunchKernelGGL(k_matvec, dim3(Q / 16), dim3(256), 0, stream,
                       embed, phiw, packed, abc, PIDX[si]);
    hipLaunchKernelGGL(k_apply, dim3((B_ * 16 * L_) / 256), dim3(256), 0, stream,
                       f, embed, phib, packed, abc, fhat, lossac,
                       s, log2blk, blk, PIDX[si], si);
  }
  hipLaunchKernelGGL(k_loss, dim3(1), dim3(64), 0, stream, lossac, fhat);
}

// Round 3
// 925.721 us; speedup vs baseline: 1.0921x; 1.0921x over previous
//
#include <hip/hip_runtime.h>

// VectorQuantizer (VAR-style multi-scale residual VQ) forward on gfx950.
// R3: argmax via MFMA with 3-term fp16 split, low terms pre-scaled by 2^11/2^22
// so all stored fp16 values are normal (R2 failed on subnormal flush of the
// 2-term split's low parts). Three fp32 accumulators, combined in epilogue.

#define B_ 32
#define C_ 64
#define L_ 512
#define V_ 8192

typedef _Float16 half8 __attribute__((ext_vector_type(8)));
typedef float f32x4 __attribute__((ext_vector_type(4)));

#define C11 4.8828125e-4f  // 2^-11

__device__ __forceinline__ unsigned enc_f(float s) {
  unsigned u = __float_as_uint(s);
  return (u & 0x80000000u) ? ~u : (u | 0x80000000u);
}

__device__ __forceinline__ void split3(float x, _Float16& h, _Float16& m,
                                       _Float16& l) {
  h = (_Float16)x;
  float r1 = x - (float)h;            // exact (13-bit result)
  m = (_Float16)(r1 * 2048.0f);       // scaled into normal range
  float r2 = r1 - (float)m * C11;     // exact
  l = (_Float16)(r2 * 4194304.0f);    // * 2^22
}

// ---------- prep: normalize codebook rows (fp32), 3-way split, [V][64] ----------
__global__ __launch_bounds__(256) void k_prep(const float* __restrict__ embed,
                                              _Float16* __restrict__ ch,
                                              _Float16* __restrict__ cm,
                                              _Float16* __restrict__ cl) {
  int g = blockIdx.x * 256 + threadIdx.x;  // 4 lanes per code
  int v = g >> 2;
  int sub = g & 3;
  if (v >= V_) return;
  const float* row = embed + v * 64 + sub * 16;
  float x[16];
  float ss = 0.f;
#pragma unroll
  for (int i = 0; i < 16; i += 4) {
    float4 t = *(const float4*)(row + i);
    x[i] = t.x; x[i + 1] = t.y; x[i + 2] = t.z; x[i + 3] = t.w;
    ss += t.x * t.x + t.y * t.y + t.z * t.z + t.w * t.w;
  }
  ss += __shfl_xor(ss, 1);
  ss += __shfl_xor(ss, 2);
  float rinv = 1.0f / fmaxf(sqrtf(ss), 1e-12f);
  _Float16 hb[16], mb[16], lb[16];
#pragma unroll
  for (int i = 0; i < 16; i++) split3(x[i] * rinv, hb[i], mb[i], lb[i]);
  const int o = v * 64 + sub * 16;
  *(half8*)(ch + o) = *(half8*)(hb);
  *(half8*)(ch + o + 8) = *(half8*)(hb + 8);
  *(half8*)(cm + o) = *(half8*)(mb);
  *(half8*)(cm + o + 8) = *(half8*)(mb + 8);
  *(half8*)(cl + o) = *(half8*)(lb);
  *(half8*)(cl + o + 8) = *(half8*)(lb + 8);
}

// ---------- init: zero f_hat (in d_out) and loss accumulators ----------
__global__ __launch_bounds__(256) void k_init(float* __restrict__ fhat,
                                              float* __restrict__ lossac) {
  int i = blockIdx.x * 256 + threadIdx.x;
  if (i < B_ * C_ * L_) fhat[i] = 0.0f;
  if (i < 16) lossac[i] = 0.0f;
}

// ---------- downsample residual (f - f_hat) to [C][Q] (transposed), zero packed ----------
__global__ __launch_bounds__(256) void k_down(const float* __restrict__ f,
                                              const float* __restrict__ fhat,
                                              float* __restrict__ restqT,
                                              unsigned long long* __restrict__ packed,
                                              int Q, int log2Q, int log2s, int blk) {
  int g = blockIdx.x * 256 + threadIdx.x;  // Q*64 threads
  int q = g & (Q - 1);
  int c = g >> log2Q;
  int b = q >> log2s;
  int j = q - (b << log2s);
  const int base = ((b << 6) + c) * L_ + j * blk;
  float s0 = 0.f, s1 = 0.f, s2 = 0.f, s3 = 0.f;
  int t = 0;
  for (; t + 4 <= blk; t += 4) {
    s0 += f[base + t]     - fhat[base + t];
    s1 += f[base + t + 1] - fhat[base + t + 1];
    s2 += f[base + t + 2] - fhat[base + t + 2];
    s3 += f[base + t + 3] - fhat[base + t + 3];
  }
  for (; t < blk; t++) s0 += f[base + t] - fhat[base + t];
  restqT[c * Q + q] = ((s0 + s1) + (s2 + s3)) * (1.0f / (float)blk);
  if (g < Q) packed[g] = 0ull;
}

// ---------- MFMA argmax, 3-term split, 3 accumulators ----------
template <int MT>
__global__ __launch_bounds__(256) void k_argmax3(
    const _Float16* __restrict__ ch, const _Float16* __restrict__ cm,
    const _Float16* __restrict__ cl, const float* __restrict__ restqT,
    unsigned long long* __restrict__ packed, int Q, int mgroups, int wave_codes) {
  const int mg = blockIdx.x % mgroups;
  const int sp = blockIdx.x / mgroups;
  const int lane = threadIdx.x & 63;
  const int wave = threadIdx.x >> 6;
  const int qbase = mg * (MT * 16);
  __shared__ _Float16 qh[MT * 16][72];  // stride 144B = 16B-aligned
  __shared__ _Float16 qm[MT * 16][72];
  __shared__ _Float16 ql[MT * 16][72];
  for (int i = threadIdx.x; i < MT * 16 * 64; i += 256) {
    int c = i / (MT * 16);
    int qq = i % (MT * 16);
    float v = restqT[c * Q + qbase + qq];
    _Float16 h, m, l;
    split3(v, h, m, l);
    qh[qq][c] = h;
    qm[qq][c] = m;
    ql[qq][c] = l;
  }
  __syncthreads();

  const int m = lane & 15;
  const int quad = lane >> 4;
  half8 ah[MT][2], am[MT][2], al[MT][2];
#pragma unroll
  for (int mt = 0; mt < MT; mt++)
#pragma unroll
    for (int kc = 0; kc < 2; kc++) {
      ah[mt][kc] = *(const half8*)(&qh[mt * 16 + m][kc * 32 + quad * 8]);
      am[mt][kc] = *(const half8*)(&qm[mt * 16 + m][kc * 32 + quad * 8]);
      al[mt][kc] = *(const half8*)(&ql[mt * 16 + m][kc * 32 + quad * 8]);
    }

  float best[MT][4];
  int bidx[MT][4];
#pragma unroll
  for (int mt = 0; mt < MT; mt++)
#pragma unroll
    for (int r = 0; r < 4; r++) { best[mt][r] = -3.4e38f; bidx[mt][r] = 0; }

  const int code_start = (sp * 4 + wave) * wave_codes;
  for (int t = 0; t < wave_codes; t += 16) {
    const int code0 = code_start + t;
    const int co = (code0 + m) * 64 + quad * 8;
    const half8 bh0 = *(const half8*)(ch + co);
    const half8 bh1 = *(const half8*)(ch + co + 32);
    const half8 bm0 = *(const half8*)(cm + co);
    const half8 bm1 = *(const half8*)(cm + co + 32);
    const half8 bl0 = *(const half8*)(cl + co);
    const half8 bl1 = *(const half8*)(cl + co + 32);
    const int cid = code0 + m;
#pragma unroll
    for (int mt = 0; mt < MT; mt++) {
      f32x4 a0 = {0.f, 0.f, 0.f, 0.f};
      f32x4 a1 = {0.f, 0.f, 0.f, 0.f};
      f32x4 a2 = {0.f, 0.f, 0.f, 0.f};
      a0 = __builtin_amdgcn_mfma_f32_16x16x32_f16(ah[mt][0], bh0, a0, 0, 0, 0);
      a1 = __builtin_amdgcn_mfma_f32_16x16x32_f16(ah[mt][0], bm0, a1, 0, 0, 0);
      a2 = __builtin_amdgcn_mfma_f32_16x16x32_f16(ah[mt][0], bl0, a2, 0, 0, 0);
      a0 = __builtin_amdgcn_mfma_f32_16x16x32_f16(ah[mt][1], bh1, a0, 0, 0, 0);
      a1 = __builtin_amdgcn_mfma_f32_16x16x32_f16(am[mt][0], bh0, a1, 0, 0, 0);
      a2 = __builtin_amdgcn_mfma_f32_16x16x32_f16(al[mt][0], bh0, a2, 0, 0, 0);
      a1 = __builtin_amdgcn_mfma_f32_16x16x32_f16(ah[mt][1], bm1, a1, 0, 0, 0);
      a2 = __builtin_amdgcn_mfma_f32_16x16x32_f16(am[mt][0], bm0, a2, 0, 0, 0);
      a1 = __builtin_amdgcn_mfma_f32_16x16x32_f16(am[mt][1], bh1, a1, 0, 0, 0);
      a2 = __builtin_amdgcn_mfma_f32_16x16x32_f16(ah[mt][1], bl1, a2, 0, 0, 0);
      a2 = __builtin_amdgcn_mfma_f32_16x16x32_f16(al[mt][1], bh1, a2, 0, 0, 0);
      a2 = __builtin_amdgcn_mfma_f32_16x16x32_f16(am[mt][1], bm1, a2, 0, 0, 0);
#pragma unroll
      for (int r = 0; r < 4; r++) {
        float sc = fmaf(C11, fmaf(C11, a2[r], a1[r]), a0[r]);
        if (sc > best[mt][r]) { best[mt][r] = sc; bidx[mt][r] = cid; }
      }
    }
  }
#pragma unroll
  for (int off = 1; off < 16; off <<= 1) {
#pragma unroll
    for (int mt = 0; mt < MT; mt++)
#pragma unroll
      for (int r = 0; r < 4; r++) {
        float ob = __shfl_xor(best[mt][r], off);
        int oi = __shfl_xor(bidx[mt][r], off);
        if (ob > best[mt][r] || (ob == best[mt][r] && oi < bidx[mt][r])) {
          best[mt][r] = ob; bidx[mt][r] = oi;
        }
      }
  }
  if (m == 0) {
#pragma unroll
    for (int mt = 0; mt < MT; mt++)
#pragma unroll
      for (int r = 0; r < 4; r++) {
        unsigned long long pk =
            ((unsigned long long)enc_f(best[mt][r]) << 32) |
            (unsigned)(~bidx[mt][r]);
        atomicMax(&packed[qbase + mt * 16 + quad * 4 + r], pk);
      }
  }
}

// ---------- per-segment conv matvecs: abc[q][192] = {W_-1 h, W_0 h, W_+1 h} ----------
__global__ __launch_bounds__(256) void k_matvec(const float* __restrict__ embed,
                                                const float* __restrict__ phiw,
                                                const unsigned long long* __restrict__ packed,
                                                float* __restrict__ abc,
                                                int pidx) {
  __shared__ float wl[3][64][65];
  __shared__ float hl[64][16];
  const float* pw = phiw + pidx * (64 * 64 * 3);
  for (int i = threadIdx.x; i < 64 * 64 * 3; i += 256) {
    int o = i / 192;
    int r = i - o * 192;
    int c = r / 3;
    int t = r - c * 3;
    wl[t][c][o] = pw[i];
  }
  const int qbase = blockIdx.x * 16;
  for (int i = threadIdx.x; i < 16 * 64; i += 256) {
    int qq = i & 15, c = i >> 4;
    int idx = (int)(~(unsigned)(packed[qbase + qq]));
    hl[c][qq] = embed[idx * C_ + c];
  }
  __syncthreads();

  const int o = threadIdx.x & 63;
  const int q0 = (threadIdx.x >> 6) * 4;
  float a0[3][4];
#pragma unroll
  for (int t = 0; t < 3; t++)
#pragma unroll
    for (int qq = 0; qq < 4; qq++) a0[t][qq] = 0.0f;

#pragma unroll 4
  for (int c = 0; c < 64; c++) {
    const float4 h4 = *(const float4*)(&hl[c][q0]);
    const float w0 = wl[0][c][o], w1 = wl[1][c][o], w2 = wl[2][c][o];
    const float hv[4] = {h4.x, h4.y, h4.z, h4.w};
#pragma unroll
    for (int qq = 0; qq < 4; qq++) {
      a0[0][qq] = fmaf(w0, hv[qq], a0[0][qq]);
      a0[1][qq] = fmaf(w1, hv[qq], a0[1][qq]);
      a0[2][qq] = fmaf(w2, hv[qq], a0[2][qq]);
    }
  }
#pragma unroll
  for (int t = 0; t < 3; t++)
#pragma unroll
    for (int qq = 0; qq < 4; qq++)
      abc[(qbase + q0 + qq) * 192 + t * 64 + o] = a0[t][qq];
}

// ---------- apply: h_out = 0.5h + 0.5(conv+bias); f_hat += h_out; loss partial ----------
__global__ __launch_bounds__(256) void k_apply(const float* __restrict__ f,
                                               const float* __restrict__ embed,
                                               const float* __restrict__ phib,
                                               const unsigned long long* __restrict__ packed,
                                               const float* __restrict__ abc,
                                               float* __restrict__ fhat,
                                               float* __restrict__ lossac,
                                               int s, int log2blk, int blk, int pidx, int si) {
  const int g = blockIdx.x * 256 + threadIdx.x;  // B*16*L threads
  const int l = g & 511;
  const int c4 = (g >> 9) & 15;
  const int b = g >> 13;
  const int j = l >> log2blk;
  const int pos = l & (blk - 1);
  const int q = b * s + j;
  const int idx = (int)(~(unsigned)(packed[q]));
  const bool la = (pos == 0), rc = (pos == blk - 1);
  const int ja = la ? j - 1 : j;
  const int jc = rc ? j + 1 : j;
  const int c0 = c4 * 4;

  float4 a4 = make_float4(0.f, 0.f, 0.f, 0.f);
  float4 cc4 = make_float4(0.f, 0.f, 0.f, 0.f);
  if (ja >= 0) a4 = *(const float4*)(abc + (b * s + ja) * 192 + c0);
  const float4 b4 = *(const float4*)(abc + q * 192 + 64 + c0);
  if (jc < s) cc4 = *(const float4*)(abc + (b * s + jc) * 192 + 128 + c0);
  const float4 h4 = *(const float4*)(embed + idx * C_ + c0);
  const float4 bi = *(const float4*)(phib + pidx * C_ + c0);

  const float av[4] = {a4.x, a4.y, a4.z, a4.w};
  const float bv[4] = {b4.x, b4.y, b4.z, b4.w};
  const float cv[4] = {cc4.x, cc4.y, cc4.z, cc4.w};
  const float hv[4] = {h4.x, h4.y, h4.z, h4.w};
  const float biv[4] = {bi.x, bi.y, bi.z, bi.w};

  float sq = 0.0f;
#pragma unroll
  for (int i = 0; i < 4; i++) {
    float y = ((av[i] + bv[i]) + cv[i]) + biv[i];
    float ho = 0.5f * (hv[i] + y);
    int fi = ((b << 6) + c0 + i) * L_ + l;
    float fh = fhat[fi] + ho;
    fhat[fi] = fh;
    float d = fh - f[fi];
    sq = fmaf(d, d, sq);
  }
#pragma unroll
  for (int off = 32; off > 0; off >>= 1) sq += __shfl_down(sq, off);
  __shared__ float red[4];
  const int lane = threadIdx.x & 63, wave = threadIdx.x >> 6;
  if (lane == 0) red[wave] = sq;
  __syncthreads();
  if (threadIdx.x == 0)
    atomicAdd(&lossac[si], (red[0] + red[1]) + (red[2] + red[3]));
}

// ---------- final loss ----------
__global__ void k_loss(const float* __restrict__ lossac, float* __restrict__ out) {
  if (threadIdx.x == 0 && blockIdx.x == 0) {
    float sum = 0.f;
    for (int i = 0; i < 10; i++) sum += lossac[i];
    out[B_ * C_ * L_] = sum * (1.25f / (10.0f * (float)(B_ * C_ * L_)));
  }
}

extern "C" void kernel_launch(void* const* d_in, const int* in_sizes, int n_in,
                              void* d_out, int out_size, void* d_ws, size_t ws_size,
                              hipStream_t stream) {
  const float* f     = (const float*)d_in[0];  // [32][64][512]
  const float* embed = (const float*)d_in[1];  // [8192][64]
  const float* phiw  = (const float*)d_in[2];  // [4][64][64][3]
  const float* phib  = (const float*)d_in[3];  // [4][64]
  float* fhat = (float*)d_out;                 // f_hat + loss scalar at [1048576]

  _Float16* ch = (_Float16*)d_ws;                       // V*64 halves = 1MB
  _Float16* cm = ch + V_ * 64;                          // 1MB
  _Float16* cl = cm + V_ * 64;                          // 1MB
  float* restqT = (float*)(cl + V_ * 64);               // 64*16384 fp32 = 4MB
  float* abc    = restqT + 64 * 16384;                  // 16384*192 = 12.6MB
  float* lossac = abc + 16384 * 192;                    // 16
  unsigned long long* packed = (unsigned long long*)(lossac + 16);  // 16384 u64

  k_prep<<<dim3((V_ * 4) / 256), dim3(256), 0, stream>>>(embed, ch, cm, cl);
  k_init<<<dim3((B_ * C_ * L_) / 256), dim3(256), 0, stream>>>(fhat, lossac);

  static const int SEG[10]  = {1, 2, 4, 8, 16, 32, 64, 128, 256, 512};
  static const int PIDX[10] = {0, 0, 1, 1, 1, 2, 2, 3, 3, 3};
  static const int NSPL[10] = {128, 128, 128, 64, 64, 32, 16, 16, 8, 4};

  for (int si = 0; si < 10; si++) {
    const int s = SEG[si];
    int log2s = 0;
    while ((1 << log2s) < s) log2s++;
    const int Q = 32 * s;
    const int log2Q = 5 + log2s;
    const int blk = L_ / s;
    const int log2blk = 9 - log2s;
    const int nsplit = NSPL[si];
    const int wave_codes = V_ / nsplit / 4;  // codes per wave (multiple of 16)

    k_down<<<dim3((Q * 64) / 256), dim3(256), 0, stream>>>(
        f, fhat, restqT, packed, Q, log2Q, log2s, blk);

    if (Q >= 64) {
      const int mgroups = Q / 64;
      k_argmax3<4><<<dim3(mgroups * nsplit), dim3(256), 0, stream>>>(
          ch, cm, cl, restqT, packed, Q, mgroups, wave_codes);
    } else {
      k_argmax3<2><<<dim3(nsplit), dim3(256), 0, stream>>>(
          ch, cm, cl, restqT, packed, Q, 1, wave_codes);
    }
    k_matvec<<<dim3(Q / 16), dim3(256), 0, stream>>>(embed, phiw, packed, abc, PIDX[si]);
    k_apply<<<dim3((B_ * 16 * L_) / 256), dim3(256), 0, stream>>>(
        f, embed, phib, packed, abc, fhat, lossac, s, log2blk, blk, PIDX[si], si);
  }
  k_loss<<<dim3(1), dim3(64), 0, stream>>>(lossac, fhat);
}

// Round 4
// 858.904 us; speedup vs baseline: 1.1771x; 1.0778x over previous
//
#include <hip/hip_runtime.h>

// VectorQuantizer (VAR-style multi-scale residual VQ) forward on gfx950.
// R4: launch-count attack. 22 launches (was 43): one setup kernel
// (codebook split + zeroing + scale-0 downsample), then per scale
// {argmax (MFMA, 3-term fp16 split, 10 MFMA/tile), fused matvec+apply}
// which also emits the NEXT scale's downsampled residual (as sums —
// argmax is scale-invariant in the query, so mean scaling is skipped).

#define B_ 32
#define C_ 64
#define L_ 512
#define V_ 8192

typedef _Float16 half8 __attribute__((ext_vector_type(8)));
typedef float f32x4 __attribute__((ext_vector_type(4)));

#define C11 4.8828125e-4f  // 2^-11

__device__ __forceinline__ unsigned enc_f(float s) {
  unsigned u = __float_as_uint(s);
  return (u & 0x80000000u) ? ~u : (u | 0x80000000u);
}

__device__ __forceinline__ void split3(float x, _Float16& h, _Float16& m,
                                       _Float16& l) {
  h = (_Float16)x;
  float r1 = x - (float)h;           // exact
  m = (_Float16)(r1 * 2048.0f);      // scaled into fp16 normal range
  float r2 = r1 - (float)m * C11;    // exact
  l = (_Float16)(r2 * 4194304.0f);   // * 2^22
}

// ---------- setup: codebook prep + zeroing + scale-0 downsample ----------
__global__ __launch_bounds__(256) void k_setup(
    const float* __restrict__ f, const float* __restrict__ embed,
    _Float16* __restrict__ ch, _Float16* __restrict__ cm,
    _Float16* __restrict__ cl, float* __restrict__ restAll,
    float* __restrict__ fhat, float* __restrict__ lossac,
    unsigned long long* __restrict__ packed) {
  const int blk = blockIdx.x;
  const int tid = threadIdx.x;
  if (blk < 128) {
    // normalize codebook rows (fp32), 3-way split, [V][64]
    int g = blk * 256 + tid;  // 4 lanes per code
    int v = g >> 2;
    int sub = g & 3;
    const float* row = embed + v * 64 + sub * 16;
    float x[16];
    float ss = 0.f;
#pragma unroll
    for (int i = 0; i < 16; i += 4) {
      float4 t = *(const float4*)(row + i);
      x[i] = t.x; x[i + 1] = t.y; x[i + 2] = t.z; x[i + 3] = t.w;
      ss += t.x * t.x + t.y * t.y + t.z * t.z + t.w * t.w;
    }
    ss += __shfl_xor(ss, 1);
    ss += __shfl_xor(ss, 2);
    float rinv = 1.0f / fmaxf(sqrtf(ss), 1e-12f);
    _Float16 hb[16], mb[16], lb[16];
#pragma unroll
    for (int i = 0; i < 16; i++) split3(x[i] * rinv, hb[i], mb[i], lb[i]);
    const int o = v * 64 + sub * 16;
    *(half8*)(ch + o) = *(half8*)(hb);
    *(half8*)(ch + o + 8) = *(half8*)(hb + 8);
    *(half8*)(cm + o) = *(half8*)(mb);
    *(half8*)(cm + o + 8) = *(half8*)(mb + 8);
    *(half8*)(cl + o) = *(half8*)(lb);
    *(half8*)(cl + o + 8) = *(half8*)(lb + 8);
  } else if (blk < 640) {
    // scale-0 downsample: rest0[c*32 + b] = sum_l f[b][c][l]
    int sb = blk - 128;           // 512 blocks: 32 b x 16 c-groups
    int b = sb >> 4;
    int c = (sb & 15) * 4 + (tid >> 6);
    int lane = tid & 63;
    const float* row = f + (b * 64 + c) * 512 + lane * 8;
    float4 x0 = *(const float4*)row;
    float4 x1 = *(const float4*)(row + 4);
    float ssum = ((x0.x + x0.y) + (x0.z + x0.w)) +
                 ((x1.x + x1.y) + (x1.z + x1.w));
#pragma unroll
    for (int off = 32; off > 0; off >>= 1) ssum += __shfl_down(ssum, off);
    if (lane == 0) restAll[c * 32 + b] = ssum;
  } else {
    // zero: fhat, atomic rest slices (scales 1..5), packed, lossac
    int zg = (blk - 640) * 256 + tid;
    const int ZS = 2048 * 256;
    for (int i = zg; i < B_ * C_ * L_; i += ZS) fhat[i] = 0.0f;
    for (int i = zg; i < 126976; i += ZS) restAll[2048 + i] = 0.0f;
    for (int i = zg; i < 32736; i += ZS) packed[i] = 0ull;
    if (zg < 16) lossac[zg] = 0.0f;
  }
}

// ---------- MFMA argmax, 3-term split, 3 accumulators, 10 MFMA/tile ----------
template <int MT>
__global__ __launch_bounds__(256) void k_argmax3(
    const _Float16* __restrict__ ch, const _Float16* __restrict__ cm,
    const _Float16* __restrict__ cl, const float* __restrict__ restq,
    unsigned long long* __restrict__ packedq, int Q, int mgroups,
    int wave_codes) {
  const int mg = blockIdx.x % mgroups;
  const int sp = blockIdx.x / mgroups;
  const int lane = threadIdx.x & 63;
  const int wave = threadIdx.x >> 6;
  const int qbase = mg * (MT * 16);
  __shared__ _Float16 qh[MT * 16][72];  // stride 144B = 16B-aligned
  __shared__ _Float16 qm[MT * 16][72];
  __shared__ _Float16 ql[MT * 16][72];
  for (int i = threadIdx.x; i < MT * 16 * 64; i += 256) {
    int c = i / (MT * 16);
    int qq = i % (MT * 16);
    float v = restq[c * Q + qbase + qq];
    _Float16 h, m, l;
    split3(v, h, m, l);
    qh[qq][c] = h;
    qm[qq][c] = m;
    ql[qq][c] = l;
  }
  __syncthreads();

  const int m = lane & 15;
  const int quad = lane >> 4;
  half8 ah[MT][2], am[MT][2], al[MT][2];
#pragma unroll
  for (int mt = 0; mt < MT; mt++)
#pragma unroll
    for (int kc = 0; kc < 2; kc++) {
      ah[mt][kc] = *(const half8*)(&qh[mt * 16 + m][kc * 32 + quad * 8]);
      am[mt][kc] = *(const half8*)(&qm[mt * 16 + m][kc * 32 + quad * 8]);
      al[mt][kc] = *(const half8*)(&ql[mt * 16 + m][kc * 32 + quad * 8]);
    }

  float best[MT][4];
  int bidx[MT][4];
#pragma unroll
  for (int mt = 0; mt < MT; mt++)
#pragma unroll
    for (int r = 0; r < 4; r++) { best[mt][r] = -3.4e38f; bidx[mt][r] = 0; }

  const int code_start = (sp * 4 + wave) * wave_codes;
  for (int t = 0; t < wave_codes; t += 16) {
    const int code0 = code_start + t;
    const int co = (code0 + m) * 64 + quad * 8;
    const half8 bh0 = *(const half8*)(ch + co);
    const half8 bh1 = *(const half8*)(ch + co + 32);
    const half8 bm0 = *(const half8*)(cm + co);
    const half8 bm1 = *(const half8*)(cm + co + 32);
    const half8 bl0 = *(const half8*)(cl + co);
    const half8 bl1 = *(const half8*)(cl + co + 32);
    const int cid = code0 + m;
#pragma unroll
    for (int mt = 0; mt < MT; mt++) {
      f32x4 a0 = {0.f, 0.f, 0.f, 0.f};
      f32x4 a1 = {0.f, 0.f, 0.f, 0.f};
      f32x4 a2 = {0.f, 0.f, 0.f, 0.f};
      a0 = __builtin_amdgcn_mfma_f32_16x16x32_f16(ah[mt][0], bh0, a0, 0, 0, 0);
      a1 = __builtin_amdgcn_mfma_f32_16x16x32_f16(ah[mt][0], bm0, a1, 0, 0, 0);
      a2 = __builtin_amdgcn_mfma_f32_16x16x32_f16(ah[mt][0], bl0, a2, 0, 0, 0);
      a0 = __builtin_amdgcn_mfma_f32_16x16x32_f16(ah[mt][1], bh1, a0, 0, 0, 0);
      a1 = __builtin_amdgcn_mfma_f32_16x16x32_f16(am[mt][0], bh0, a1, 0, 0, 0);
      a2 = __builtin_amdgcn_mfma_f32_16x16x32_f16(al[mt][0], bh0, a2, 0, 0, 0);
      a1 = __builtin_amdgcn_mfma_f32_16x16x32_f16(ah[mt][1], bm1, a1, 0, 0, 0);
      a1 = __builtin_amdgcn_mfma_f32_16x16x32_f16(am[mt][1], bh1, a1, 0, 0, 0);
      a2 = __builtin_amdgcn_mfma_f32_16x16x32_f16(ah[mt][1], bl1, a2, 0, 0, 0);
      a2 = __builtin_amdgcn_mfma_f32_16x16x32_f16(al[mt][1], bh1, a2, 0, 0, 0);
#pragma unroll
      for (int r = 0; r < 4; r++) {
        float sc = fmaf(C11, fmaf(C11, a2[r], a1[r]), a0[r]);
        if (sc > best[mt][r]) { best[mt][r] = sc; bidx[mt][r] = cid; }
      }
    }
  }
#pragma unroll
  for (int off = 1; off < 16; off <<= 1) {
#pragma unroll
    for (int mt = 0; mt < MT; mt++)
#pragma unroll
      for (int r = 0; r < 4; r++) {
        float ob = __shfl_xor(best[mt][r], off);
        int oi = __shfl_xor(bidx[mt][r], off);
        if (ob > best[mt][r] || (ob == best[mt][r] && oi < bidx[mt][r])) {
          best[mt][r] = ob; bidx[mt][r] = oi;
        }
      }
  }
  if (m == 0) {
#pragma unroll
    for (int mt = 0; mt < MT; mt++)
#pragma unroll
      for (int r = 0; r < 4; r++) {
        unsigned long long pk =
            ((unsigned long long)enc_f(best[mt][r]) << 32) |
            (unsigned)(~bidx[mt][r]);
        atomicMax(&packedq[qbase + mt * 16 + quad * 4 + r], pk);
      }
  }
}

// ---------- fused: per-block matvec (+halo) -> apply -> loss + next rest ----------
// block = (l-chunk of 32, batch). LDS abc for local segments only.
__global__ __launch_bounds__(256) void k_fused(
    const float* __restrict__ f, const float* __restrict__ embed,
    const float* __restrict__ phiw, const float* __restrict__ phib,
    const unsigned long long* __restrict__ packedq,
    float* __restrict__ restn, float* __restrict__ fhat,
    float* __restrict__ lossac, int s, int log2blk, int pidx, int si,
    int log2blkn) {
  const int ch0 = blockIdx.x * 32;
  const int bb = blockIdx.y;
  const int tid = threadIdx.x;
  const int blkw = 1 << log2blk;
  int j_lo = (ch0 >> log2blk) - 1;
  if (j_lo < 0) j_lo = 0;
  int j_hi = ((ch0 + 31) >> log2blk) + 1;
  if (j_hi > s - 1) j_hi = s - 1;
  const int nseg = j_hi - j_lo + 1;  // <= 34

  __shared__ float hl[34][64];
  __shared__ float abc_l[34][192];

  for (int i = tid; i < nseg * 64; i += 256) {
    int seg = i >> 6, c = i & 63;
    int idx = (int)(~(unsigned)(packedq[bb * s + j_lo + seg]));
    hl[seg][c] = embed[idx * 64 + c];
  }
  __syncthreads();

  // matvec: lane o owns output channel o; waves stride over segments
  {
    const int o = tid & 63;
    const int w4 = tid >> 6;
    const float* wrow = phiw + (pidx * 64 + o) * 192;  // [c][t] row
    float acc[9][3];
#pragma unroll
    for (int a = 0; a < 9; a++) { acc[a][0] = acc[a][1] = acc[a][2] = 0.f; }
#pragma unroll
    for (int c4b = 0; c4b < 4; c4b++) {
      float w48[48];
#pragma unroll
      for (int k = 0; k < 12; k++)
        *(float4*)(w48 + 4 * k) = *(const float4*)(wrow + c4b * 48 + 4 * k);
#pragma unroll
      for (int sx = 0; sx < 9; sx++) {
        int seg = w4 + sx * 4;
        if (seg < nseg) {
#pragma unroll
          for (int cc4 = 0; cc4 < 4; cc4++) {
            float4 h4 = *(const float4*)(&hl[seg][c4b * 16 + cc4 * 4]);
            const float hv[4] = {h4.x, h4.y, h4.z, h4.w};
#pragma unroll
            for (int u = 0; u < 4; u++) {
              int cc = cc4 * 4 + u;
              acc[sx][0] = fmaf(w48[cc * 3 + 0], hv[u], acc[sx][0]);
              acc[sx][1] = fmaf(w48[cc * 3 + 1], hv[u], acc[sx][1]);
              acc[sx][2] = fmaf(w48[cc * 3 + 2], hv[u], acc[sx][2]);
            }
          }
        }
      }
    }
#pragma unroll
    for (int sx = 0; sx < 9; sx++) {
      int seg = w4 + sx * 4;
      if (seg < nseg) {
        abc_l[seg][o] = acc[sx][0];
        abc_l[seg][64 + o] = acc[sx][1];
        abc_l[seg][128 + o] = acc[sx][2];
      }
    }
  }
  __syncthreads();

  // apply: thread = (c, 8 consecutive l)
  const int c = tid >> 2;
  const int l0 = ch0 + (tid & 3) * 8;
  const float bias = phib[pidx * 64 + c];
  const int fi0 = (bb * 64 + c) * 512 + l0;
  const float4 fa = *(const float4*)(f + fi0);
  const float4 fb2 = *(const float4*)(f + fi0 + 4);
  const float4 ga = *(const float4*)(fhat + fi0);
  const float4 gb2 = *(const float4*)(fhat + fi0 + 4);
  float fv[8] = {fa.x, fa.y, fa.z, fa.w, fb2.x, fb2.y, fb2.z, fb2.w};
  float fhv[8] = {ga.x, ga.y, ga.z, ga.w, gb2.x, gb2.y, gb2.z, gb2.w};
  float dv[8];
  float sq = 0.f;
#pragma unroll
  for (int k = 0; k < 8; k++) {
    int l = l0 + k;
    int j = l >> log2blk;
    int jrel = j - j_lo;
    int pos = l & (blkw - 1);
    float y = abc_l[jrel][64 + c] + bias;
    if (pos == 0) {
      if (j > 0) y += abc_l[jrel - 1][c];
    } else {
      y += abc_l[jrel][c];
    }
    if (pos == blkw - 1) {
      if (j < s - 1) y += abc_l[jrel + 1][128 + c];
    } else {
      y += abc_l[jrel][128 + c];
    }
    float ho = 0.5f * (hl[jrel][c] + y);
    float fh = fhv[k] + ho;
    fhv[k] = fh;
    float d = fh - fv[k];
    dv[k] = d;
    sq = fmaf(d, d, sq);
  }
  *(float4*)(fhat + fi0) = make_float4(fhv[0], fhv[1], fhv[2], fhv[3]);
  *(float4*)(fhat + fi0 + 4) = make_float4(fhv[4], fhv[5], fhv[6], fhv[7]);

  // next-scale rest (sums; argmax is scale-invariant in the query)
  if (log2blkn >= 0) {
    const int sn = 512 >> log2blkn;
    const int blkn = 1 << log2blkn;
    const int qb = c * (32 * sn) + bb * sn;
    if (blkn >= 16) {  // slices 1..5 pre-zeroed; cross-thread/block sums
      float rs = -(((dv[0] + dv[1]) + (dv[2] + dv[3])) +
                   ((dv[4] + dv[5]) + (dv[6] + dv[7])));
      atomicAdd(&restn[qb + (l0 >> log2blkn)], rs);
    } else if (blkn == 8) {
      float rs = -(((dv[0] + dv[1]) + (dv[2] + dv[3])) +
                   ((dv[4] + dv[5]) + (dv[6] + dv[7])));
      restn[qb + (l0 >> 3)] = rs;
    } else {
      for (int base = 0; base < 8; base += blkn) {
        float rs = 0.f;
        for (int k = 0; k < blkn; k++) rs += dv[base + k];
        restn[qb + ((l0 + base) >> log2blkn)] = -rs;
      }
    }
  }

  // loss partial
#pragma unroll
  for (int off = 32; off > 0; off >>= 1) sq += __shfl_down(sq, off);
  __shared__ float red[4];
  const int lane = tid & 63, wave = tid >> 6;
  if (lane == 0) red[wave] = sq;
  __syncthreads();
  if (tid == 0)
    atomicAdd(&lossac[si], (red[0] + red[1]) + (red[2] + red[3]));
}

// ---------- final loss ----------
__global__ void k_loss(const float* __restrict__ lossac,
                       float* __restrict__ out) {
  if (threadIdx.x == 0 && blockIdx.x == 0) {
    float sum = 0.f;
    for (int i = 0; i < 10; i++) sum += lossac[i];
    out[B_ * C_ * L_] = sum * (1.25f / (10.0f * (float)(B_ * C_ * L_)));
  }
}

extern "C" void kernel_launch(void* const* d_in, const int* in_sizes, int n_in,
                              void* d_out, int out_size, void* d_ws,
                              size_t ws_size, hipStream_t stream) {
  const float* f     = (const float*)d_in[0];  // [32][64][512]
  const float* embed = (const float*)d_in[1];  // [8192][64]
  const float* phiw  = (const float*)d_in[2];  // [4][64][64][3]
  const float* phib  = (const float*)d_in[3];  // [4][64]
  float* fhat = (float*)d_out;                 // f_hat + loss at [1048576]

  _Float16* ch = (_Float16*)d_ws;                  // V*64
  _Float16* cm = ch + V_ * 64;
  _Float16* cl = cm + V_ * 64;
  float* restAll = (float*)(cl + V_ * 64);         // 2048*1023 floats
  float* lossac = restAll + 2048 * 1023;           // 16
  unsigned long long* packed = (unsigned long long*)(lossac + 16);  // 32736

  static const int PIDX[10] = {0, 0, 1, 1, 1, 2, 2, 3, 3, 3};
  static const int NSPL[10] = {128, 128, 128, 64, 64, 32, 16, 16, 8, 4};

  k_setup<<<dim3(2688), dim3(256), 0, stream>>>(f, embed, ch, cm, cl, restAll,
                                                fhat, lossac, packed);

  for (int si = 0; si < 10; si++) {
    const int s = 1 << si;
    const int Q = 32 * s;
    const int log2blk = 9 - si;
    const int nsplit = NSPL[si];
    const int wave_codes = V_ / nsplit / 4;
    const int roff = 2048 * (s - 1);
    const int poff = 32 * (s - 1);
    const float* restq = restAll + roff;
    unsigned long long* pq = packed + poff;

    if (Q >= 64) {
      const int mgroups = Q / 64;
      k_argmax3<4><<<dim3(mgroups * nsplit), dim3(256), 0, stream>>>(
          ch, cm, cl, restq, pq, Q, mgroups, wave_codes);
    } else {
      k_argmax3<2><<<dim3(nsplit), dim3(256), 0, stream>>>(
          ch, cm, cl, restq, pq, Q, 1, wave_codes);
    }

    float* restn = (si < 9) ? (restAll + 2048 * (2 * s - 1)) : nullptr;
    const int log2blkn = (si < 9) ? (8 - si) : -1;
    k_fused<<<dim3(16, 32), dim3(256), 0, stream>>>(
        f, embed, phiw, phib, pq, restn, fhat, lossac, s, log2blk, PIDX[si],
        si, log2blkn);
  }
  k_loss<<<dim3(1), dim3(64), 0, stream>>>(lossac, fhat);
}